// Round 7
// baseline (176.075 us; speedup 1.0000x reference)
//
#include <hip/hip_runtime.h>
#include <hip/hip_bf16.h>
#include <hip/hip_fp16.h>
#include <cstdint>

#define DEVINL __device__ __forceinline__

typedef __attribute__((ext_vector_type(4))) float floatx4;
typedef __attribute__((ext_vector_type(8))) __bf16 bf16x8;
typedef __attribute__((ext_vector_type(4))) _Float16 half4;
typedef __attribute__((ext_vector_type(8))) _Float16 half8;
typedef __attribute__((ext_vector_type(4))) unsigned short u16x4;

DEVINL floatx4 mfma_16x16x32(bf16x8 a, bf16x8 b, floatx4 c) {
  return __builtin_amdgcn_mfma_f32_16x16x32_bf16(a, b, c, 0, 0, 0);
}
DEVINL floatx4 mfma_16x16x16_f16(half4 a, half4 b, floatx4 c) {
  return __builtin_amdgcn_mfma_f32_16x16x16f16(a, b, c, 0, 0, 0);
}

// async global->LDS, 16B per lane. LDS dest must be wave-uniform base + lane*16.
DEVINL void async_copy16(const void* g, void* l) {
  __builtin_amdgcn_global_load_lds(
      (__attribute__((address_space(1))) void*)(void*)g,
      (__attribute__((address_space(3))) void*)l, 16, 0, 0);
}

// Q scale: 1/sqrt(64) * log2(e), so softmax can use exp2 (bare v_exp_f32)
#define QSCALE 0.18033688011112042f

// XOR-swizzled fp16 64x64 scratch layout (row d, col s), 8 KB, conflict-light
#define VS(d, s) \
  ((d) * 128 + (((((s) >> 3)) ^ ((d) & 7)) << 4) + ((s) & 7) * 2)

// ---------------------------------------------------------------------------
// prep: one launch does x->bf16 cast (z==4) AND the four 1024x1024 weight
// transpose+casts (z=0..3). Grid (32,32,5), block (32,8).
// ---------------------------------------------------------------------------
__global__ void prep(const float* __restrict__ x, const float* __restrict__ Wq,
                     const float* __restrict__ Wk, const float* __restrict__ Wv,
                     const float* __restrict__ Wo,
                     __hip_bfloat16* __restrict__ xb,
                     __hip_bfloat16* __restrict__ Wt,
                     __hip_bfloat16* __restrict__ Wot) {
  const int z = blockIdx.z;
  const int tx = threadIdx.x, ty = threadIdx.y;  // (32,8)
  if (z == 4) {
    const int bi = blockIdx.y * 32 + blockIdx.x;   // [0,1024)
    const int tid = ty * 32 + tx;                  // [0,256)
    const int base = bi * 4096 + tid * 4;
#pragma unroll
    for (int j = 0; j < 4; ++j) {
      const int i = base + j * 1024;
      const float4 v = *(const float4*)&x[i];
      xb[i + 0] = __float2bfloat16(v.x);
      xb[i + 1] = __float2bfloat16(v.y);
      xb[i + 2] = __float2bfloat16(v.z);
      xb[i + 3] = __float2bfloat16(v.w);
    }
    return;
  }
  __shared__ float tile[32][33];
  const float* W = (z == 0) ? Wq : (z == 1) ? Wk : (z == 2) ? Wv : Wo;
  __hip_bfloat16* dst = (z < 3) ? (Wt + ((int64_t)z << 20)) : Wot;
  const int k0 = blockIdx.x * 32, n0 = blockIdx.y * 32;
#pragma unroll
  for (int i = 0; i < 32; i += 8)
    tile[ty + i][tx] = W[(int64_t)(k0 + ty + i) * 1024 + n0 + tx];
  __syncthreads();
#pragma unroll
  for (int i = 0; i < 32; i += 8)
    dst[(int64_t)(n0 + ty + i) * 1024 + k0 + tx] =
        __float2bfloat16(tile[tx][ty + i]);
}

// ---------------------------------------------------------------------------
// GEMM: C[M][N] = A[M][K] * Bt[N][K]^T  (bf16, MFMA 16x16x32), BK=64,
// XOR-swizzled LDS staging (chunk ^= row&7). TM x TN tile, 256 threads.
// MODE 0 (128x128, OCC=3): QKV epilogue. 768 blocks at 3 blocks/CU are all
//   co-resident in ONE dispatch round. VGPR cap 170 > ~130 live: no spill
//   expected -- canary is WRITE_SIZE (must stay ~24 MB).
// MODE 1 (128x64, OCC=2): plain fp32 store; 512 blocks = 1 round at 2/CU.
// ---------------------------------------------------------------------------
template <int MODE, int TM, int TN, int OCC>
__global__ __launch_bounds__(256, OCC) void gemm_bt(
    const __hip_bfloat16* __restrict__ A, const __hip_bfloat16* __restrict__ Bt,
    int M, int N, int K, const float* __restrict__ bq,
    const float* __restrict__ bk, const float* __restrict__ bv,
    __hip_bfloat16* __restrict__ Qb, __hip_bfloat16* __restrict__ Kb,
    _Float16* __restrict__ Vt, float* __restrict__ outf) {
  constexpr int MI = TM / 32, NJ = TN / 32;  // acc tile dims per wave
  __shared__ __align__(16) char As[TM * 128];  // TM rows x 64 bf16
  __shared__ __align__(16) char Bs[TN * 128];
  const int tid = threadIdx.x;
  const int wave = tid >> 6, lane = tid & 63;
  const int quad = lane >> 4, l16 = lane & 15;
  const int bm = blockIdx.x * TM, bn = blockIdx.y * TN;
  const int wm = (wave >> 1) * (TM / 2), wn = (wave & 1) * (TN / 2);
  const int sw = l16 & 7;

  floatx4 acc[MI][NJ] = {};

  for (int k0 = 0; k0 < K; k0 += 64) {
#pragma unroll
    for (int i = 0; i < TM / 32; ++i) {
      const int p = tid + i * 256;
      const int r = p >> 3, cc = (p & 7) ^ (r & 7);
      async_copy16(A + (int64_t)(bm + r) * K + k0 + cc * 8, As + p * 16);
    }
#pragma unroll
    for (int i = 0; i < TN / 32; ++i) {
      const int p = tid + i * 256;
      const int r = p >> 3, cc = (p & 7) ^ (r & 7);
      async_copy16(Bt + (int64_t)(bn + r) * K + k0 + cc * 8, Bs + p * 16);
    }
    __syncthreads();
    bf16x8 af[MI][2], bfr[NJ][2];
#pragma unroll
    for (int i = 0; i < MI; ++i)
#pragma unroll
      for (int h = 0; h < 2; ++h)
        af[i][h] = *(const bf16x8*)(As + (wm + i * 16 + l16) * 128 +
                                    (((h * 4 + quad) ^ sw) << 4));
#pragma unroll
    for (int j = 0; j < NJ; ++j)
#pragma unroll
      for (int h = 0; h < 2; ++h)
        bfr[j][h] = *(const bf16x8*)(Bs + (wn + j * 16 + l16) * 128 +
                                     (((h * 4 + quad) ^ sw) << 4));
#pragma unroll
    for (int i = 0; i < MI; ++i)
#pragma unroll
      for (int j = 0; j < NJ; ++j)
#pragma unroll
        for (int h = 0; h < 2; ++h)
          acc[i][j] = mfma_16x16x32(af[i][h], bfr[j][h], acc[i][j]);
    __syncthreads();
  }

  if (MODE == 1) {
#pragma unroll
    for (int i = 0; i < MI; ++i)
#pragma unroll
      for (int j = 0; j < NJ; ++j) {
        const int n = bn + wn + j * 16 + l16;
#pragma unroll
        for (int r = 0; r < 4; ++r) {
          const int m = bm + wm + i * 16 + quad * 4 + r;
          outf[(int64_t)m * N + n] = acc[i][j][r];
        }
      }
  } else if (bn < 2048) {
    // ---- Q / K epilogue: bias (+QSCALE for Q), bf16 [B,H,S,64] ----
#pragma unroll
    for (int i = 0; i < MI; ++i)
#pragma unroll
      for (int j = 0; j < NJ; ++j) {
        const int n = bn + wn + j * 16 + l16;
        const int which = n >> 10, nn = n & 1023;
        const int h = nn >> 6, d = nn & 63;
        const float* bias = (which == 0) ? bq : bk;
#pragma unroll
        for (int r = 0; r < 4; ++r) {
          const int m = bm + wm + i * 16 + quad * 4 + r;
          const int b = m >> 11, s = m & 2047;
          float v = acc[i][j][r] + bias[nn];
          if (which == 0) v *= QSCALE;
          ((which == 0) ? Qb : Kb)[((int64_t)(b * 16 + h) * 2048 + s) * 64 + d] =
              __float2bfloat16(v);
        }
      }
  } else {
    // ---- V epilogue: LDS transpose -> Vt[B,H,64,S], coalesced rows ----
    char* scr = (wave & 1) ? Bs : As;  // >=8 KB per wave
    const int h = ((bn + wn) & 1023) >> 6;
    const int bb = (bm + wm) >> 11;
    const int sbase = (bm + wm) & 2047;
    _Float16* dstV = Vt + (int64_t)(bb * 16 + h) * 64 * 2048;
#pragma unroll
    for (int phase = 0; phase < 2; ++phase) {
      __syncthreads();
      if ((wave >> 1) == phase) {
#pragma unroll
        for (int i = 0; i < 4; ++i)
#pragma unroll
          for (int j = 0; j < 4; ++j) {
            const int d = j * 16 + l16;
#pragma unroll
            for (int r = 0; r < 4; ++r) {
              const int s = i * 16 + quad * 4 + r;
              *(_Float16*)(scr + VS(d, s)) =
                  (_Float16)(acc[i][j][r] + bv[((bn + wn) & 1023) + d]);
            }
          }
      }
      __syncthreads();
      if ((wave >> 1) == phase) {
#pragma unroll
        for (int it = 0; it < 8; ++it) {
          const int idx = lane + it * 64;  // [0,512)
          const int d = idx >> 3, sc = idx & 7;
          const half8 vv =
              *(const half8*)(scr + d * 128 + ((sc ^ (d & 7)) << 4));
          *(half8*)(dstV + (int64_t)d * 2048 + sbase + sc * 8) = vv;
        }
      }
    }
  }
}

// ---------------------------------------------------------------------------
// Flash attention v19: KVBLK=128 -- halve the barrier-iteration count, keep
// the pipelines-per-CU low.
// Model after 6 rounds: per-iteration wall ~2.8k cyc = W (~500 cyc real
// work/wave) + F (~2.3k overhead). F is NOT DMA latency (v17 counted-vmcnt
// neutral), NOT traffic (v14 -26% neutral), and NOT divisible by adding
// pipelines (v18: 2 groups x 16 iters + 4 pipelines/CU = neutral; the CU's
// per-iteration cost scales with concurrent tile-pipelines). The ONE free
// lunch observed: v14 doubled W inside existing iterations at zero cost --
// work tucked under F is free. So: 128 keys per barrier iteration as two
// sequential v13-style 64-key sub-bodies (registers reused -> ~135 VGPR).
// Longest chain: 32 -> 16 iterations. LDS 2 x 32 KB = 64 KB -> 2 blocks/CU;
// per-CU schedule ~(16+8) iteration-slots vs v13's ~(32+4).
// Even-c chunks: last tile's second half is fully beyond the diagonal ->
// skipped via block-uniform guard (k0h > c*64). Diagonal mask needed
// exactly when k0h == c*64 (holds for both parities). Per-wave store
// epilogue unchanged (each wave owns its 16 q-rows fully).
// ---------------------------------------------------------------------------
__global__ __launch_bounds__(256, 2) void attn_kernel(
    const __hip_bfloat16* __restrict__ Qb, const __hip_bfloat16* __restrict__ Kb,
    const _Float16* __restrict__ Vt, __hip_bfloat16* __restrict__ Ab) {
  // 2 bufs x 32KB: buf at b*32K; K halves at +0/+8K, V halves at +16K/+24K
  __shared__ __align__(16) char smem[65536];
  const int tid = threadIdx.x;
  const int wave = tid >> 6, lane = tid & 63;
  const int quad = lane >> 4, l16 = lane & 15;
  const int c = 31 - (int)(blockIdx.x >> 5);  // long chunks dispatch first
  const int bh = blockIdx.x & 31;
  const int qbase = c * 64 + wave * 16;  // this wave's 16 Q rows
  const int NT = (c + 2) >> 1;           // 128-key tiles (uniform per block)

  const __hip_bfloat16* Qh = Qb + (int64_t)bh * 2048 * 64;
  const __hip_bfloat16* Kh = Kb + (int64_t)bh * 2048 * 64;
  const _Float16* Vh = Vt + (int64_t)bh * 64 * 2048;

  // Q B-fragments (16x16x32): Q[qrow=l16][d=h*32+quad*8+j]
  bf16x8 qf[2];
#pragma unroll
  for (int h = 0; h < 2; ++h)
    qf[h] = *(const bf16x8*)&Qh[(int64_t)(qbase + l16) * 64 + h * 32 + quad * 8];

  floatx4 o[4] = {};  // O^T[dt][C: row=d(quad*4+r), col=qrow(l16)]
  float lsum = 0.f;

  // stage one 128-key tile (K 16KB + V 16KB) as two 64-key halves, each in
  // the exact v13 per-half layout/swizzle. 8 copies/thread.
  auto stage = [&](int buf, int k0s) {
    char* base = smem + buf * 32768;
#pragma unroll
    for (int kh = 0; kh < 2; ++kh) {
#pragma unroll
      for (int i = 0; i < 2; ++i) {
        const int p = tid + i * 256;  // [0,512)
        const int r = p >> 3, cc = (p & 7) ^ (r & 7);
        async_copy16(Kh + (int64_t)(k0s + kh * 64 + r) * 64 + cc * 8,
                     base + kh * 8192 + p * 16);
        async_copy16(Vh + (int64_t)r * 2048 + k0s + kh * 64 + cc * 8,
                     base + 16384 + kh * 8192 + p * 16);
      }
    }
  };

  stage(0, 0);
  for (int t = 0; t < NT; ++t) {
    const int k0 = t * 128;
    __syncthreads();  // buf[t&1] DMA complete; prev tile's readers done
    if (t + 1 < NT) stage((t + 1) & 1, k0 + 128);

    const char* base = smem + (t & 1) * 32768;
    const int sw = l16 & 7;

#pragma unroll
    for (int kh = 0; kh < 2; ++kh) {
      const int k0h = k0 + kh * 64;
      if (k0h > c * 64) break;  // block-uniform: half fully beyond diagonal
      const char* kb = base + kh * 8192;
      const char* vb = base + 16384 + kh * 8192;

      bf16x8 kfr[4][2];
#pragma unroll
      for (int kk = 0; kk < 4; ++kk)
#pragma unroll
        for (int h = 0; h < 2; ++h)
          kfr[kk][h] = *(const bf16x8*)(kb + (kk * 16 + l16) * 128 +
                                        (((h * 4 + quad) ^ sw) << 4));

      // S^T = K Q^T : C holds S^T[key=quad*4+r][qrow=l16]
      floatx4 st[4];
#pragma unroll
      for (int kk = 0; kk < 4; ++kk) {
        floatx4 z = {};
        z = mfma_16x16x32(kfr[kk][0], qf[0], z);
        st[kk] = mfma_16x16x32(kfr[kk][1], qf[1], z);
      }

      half4 vfr[4][4];
#pragma unroll
      for (int dt = 0; dt < 4; ++dt)
#pragma unroll
        for (int kk = 0; kk < 4; ++kk)
          vfr[dt][kk] = *(const half4*)(vb + (dt * 16 + l16) * 128 +
                                        (((kk * 2 + (quad >> 1)) ^ sw) << 4) +
                                        (quad & 1) * 8);

      // P = exp2(S), causal mask on the diagonal half; pack fp16
      const bool masked = (k0h == c * 64);
      half4 pf[4];
#pragma unroll
      for (int kk = 0; kk < 4; ++kk) {
#pragma unroll
        for (int r = 0; r < 4; ++r) {
          const int key = k0h + kk * 16 + quad * 4 + r;
          float p = __builtin_amdgcn_exp2f(st[kk][r]);
          if (masked && key > qbase + l16) p = 0.f;
          lsum += p;
          pf[kk][r] = (_Float16)p;
        }
      }

      // O^T += V^T P^T
#pragma unroll
      for (int dt = 0; dt < 4; ++dt)
#pragma unroll
        for (int kk = 0; kk < 4; ++kk)
          o[dt] = mfma_16x16x16_f16(vfr[dt][kk], pf[kk], o[dt]);
    }
  }

  // ---- finalize: l is split across the 4 quads per qrow; reduce ----
  lsum += __shfl_xor(lsum, 16, 64);
  lsum += __shfl_xor(lsum, 32, 64);
  const float invl = 1.0f / lsum;

  // store bf16 [B,S,H*64]: row = qbase+l16, cols h*64 + dt*16 + quad*4 + r
  const int b = bh >> 4, h = bh & 15;
#pragma unroll
  for (int dt = 0; dt < 4; ++dt) {
    u16x4 pack;
#pragma unroll
    for (int r = 0; r < 4; ++r)
      pack[r] = __builtin_bit_cast(unsigned short,
                                   __float2bfloat16(o[dt][r] * invl));
    *(u16x4*)&Ab[(int64_t)(b * 2048 + qbase + l16) * 1024 + h * 64 + dt * 16 +
                 quad * 4] = pack;
  }
}

// ---------------------------------------------------------------------------
// Workspace layout (bytes), needs 40 MB:
//   [0,  8M): xb  (x as bf16, 4096x1024)  -- reused as Ab (attn out) later
//   [8, 14M): Wt  (Wq|Wk|Wv transposed bf16, 3072x1024)
//   [14,16M): Wot (Wo transposed bf16, 1024x1024)
//   [16,24M): Qb  [B,H,S,64] bf16 (pre-scaled by QSCALE)
//   [24,32M): Kb  [B,H,S,64] bf16
//   [32,40M): Vt  [B,H,64,S] fp16 (written directly by gemm_bt<0> epilogue)
// ---------------------------------------------------------------------------
extern "C" void kernel_launch(void* const* d_in, const int* in_sizes, int n_in,
                              void* d_out, int out_size, void* d_ws,
                              size_t ws_size, hipStream_t stream) {
  const float* x = (const float*)d_in[0];
  const float* Wq = (const float*)d_in[1];
  const float* bq = (const float*)d_in[2];
  const float* Wk = (const float*)d_in[3];
  const float* bk = (const float*)d_in[4];
  const float* Wv = (const float*)d_in[5];
  const float* bv = (const float*)d_in[6];
  const float* Wo = (const float*)d_in[7];
  float* out = (float*)d_out;

  char* ws = (char*)d_ws;
  __hip_bfloat16* xb = (__hip_bfloat16*)(ws);
  __hip_bfloat16* Wt = (__hip_bfloat16*)(ws + (8ll << 20));
  __hip_bfloat16* Wot = (__hip_bfloat16*)(ws + (14ll << 20));
  __hip_bfloat16* Qb = (__hip_bfloat16*)(ws + (16ll << 20));
  __hip_bfloat16* Kb = (__hip_bfloat16*)(ws + (24ll << 20));
  _Float16* Vt = (_Float16*)(ws + (32ll << 20));
  __hip_bfloat16* Ab = xb;  // x dead after QKV GEMM

  prep<<<dim3(32, 32, 5), dim3(32, 8), 0, stream>>>(x, Wq, Wk, Wv, Wo, xb, Wt,
                                                    Wot);
  gemm_bt<0, 128, 128, 3><<<dim3(32, 24), 256, 0, stream>>>(
      xb, Wt, 4096, 3072, 1024, bq, bk, bv, Qb, Kb, Vt, nullptr);
  attn_kernel<<<dim3(1024), 256, 0, stream>>>(Qb, Kb, Vt, Ab);
  gemm_bt<1, 128, 64, 2><<<dim3(32, 16), 256, 0, stream>>>(
      Ab, Wot, 4096, 1024, 1024, nullptr, nullptr, nullptr, nullptr, nullptr,
      nullptr, out);
}

// Round 10
// 163.566 us; speedup vs baseline: 1.0765x; 1.0765x over previous
//
#include <hip/hip_runtime.h>
#include <hip/hip_bf16.h>
#include <hip/hip_fp16.h>
#include <cstdint>

#define DEVINL __device__ __forceinline__

typedef __attribute__((ext_vector_type(4))) float floatx4;
typedef __attribute__((ext_vector_type(8))) __bf16 bf16x8;
typedef __attribute__((ext_vector_type(4))) _Float16 half4;
typedef __attribute__((ext_vector_type(8))) _Float16 half8;
typedef __attribute__((ext_vector_type(4))) unsigned short u16x4;

DEVINL floatx4 mfma_16x16x32(bf16x8 a, bf16x8 b, floatx4 c) {
  return __builtin_amdgcn_mfma_f32_16x16x32_bf16(a, b, c, 0, 0, 0);
}
DEVINL floatx4 mfma_16x16x16_f16(half4 a, half4 b, floatx4 c) {
  return __builtin_amdgcn_mfma_f32_16x16x16f16(a, b, c, 0, 0, 0);
}

// async global->LDS, 16B per lane. LDS dest must be wave-uniform base + lane*16.
DEVINL void async_copy16(const void* g, void* l) {
  __builtin_amdgcn_global_load_lds(
      (__attribute__((address_space(1))) void*)(void*)g,
      (__attribute__((address_space(3))) void*)l, 16, 0, 0);
}

// Q scale: 1/sqrt(64) * log2(e), so softmax can use exp2 (bare v_exp_f32)
#define QSCALE 0.18033688011112042f

// XOR-swizzled fp16 64x64 scratch layout (row d, col s), 8 KB, conflict-light
#define VS(d, s) \
  ((d) * 128 + (((((s) >> 3)) ^ ((d) & 7)) << 4) + ((s) & 7) * 2)

// ---------------------------------------------------------------------------
// prep: one launch does x->bf16 cast (z==4) AND the four 1024x1024 weight
// transpose+casts (z=0..3). Grid (32,32,5), block (32,8).
// ---------------------------------------------------------------------------
__global__ void prep(const float* __restrict__ x, const float* __restrict__ Wq,
                     const float* __restrict__ Wk, const float* __restrict__ Wv,
                     const float* __restrict__ Wo,
                     __hip_bfloat16* __restrict__ xb,
                     __hip_bfloat16* __restrict__ Wt,
                     __hip_bfloat16* __restrict__ Wot) {
  const int z = blockIdx.z;
  const int tx = threadIdx.x, ty = threadIdx.y;  // (32,8)
  if (z == 4) {
    const int bi = blockIdx.y * 32 + blockIdx.x;   // [0,1024)
    const int tid = ty * 32 + tx;                  // [0,256)
    const int base = bi * 4096 + tid * 4;
#pragma unroll
    for (int j = 0; j < 4; ++j) {
      const int i = base + j * 1024;
      const float4 v = *(const float4*)&x[i];
      xb[i + 0] = __float2bfloat16(v.x);
      xb[i + 1] = __float2bfloat16(v.y);
      xb[i + 2] = __float2bfloat16(v.z);
      xb[i + 3] = __float2bfloat16(v.w);
    }
    return;
  }
  __shared__ float tile[32][33];
  const float* W = (z == 0) ? Wq : (z == 1) ? Wk : (z == 2) ? Wv : Wo;
  __hip_bfloat16* dst = (z < 3) ? (Wt + ((int64_t)z << 20)) : Wot;
  const int k0 = blockIdx.x * 32, n0 = blockIdx.y * 32;
#pragma unroll
  for (int i = 0; i < 32; i += 8)
    tile[ty + i][tx] = W[(int64_t)(k0 + ty + i) * 1024 + n0 + tx];
  __syncthreads();
#pragma unroll
  for (int i = 0; i < 32; i += 8)
    dst[(int64_t)(n0 + ty + i) * 1024 + k0 + tx] =
        __float2bfloat16(tile[tx][ty + i]);
}

// ---------------------------------------------------------------------------
// GEMM: C[M][N] = A[M][K] * Bt[N][K]^T  (bf16, MFMA 16x16x32), BK=64,
// XOR-swizzled LDS staging (chunk ^= row&7). TM x TN tile, 256 threads.
// MODE 0 (128x128, OCC=3): QKV epilogue. 768 blocks at 3 blocks/CU are all
//   co-resident in ONE dispatch round. VGPR cap 170 > ~130 live: no spill
//   expected -- canary is WRITE_SIZE (must stay ~24 MB).
// MODE 1 (128x64, OCC=2): plain fp32 store; 512 blocks = 1 round at 2/CU.
// ---------------------------------------------------------------------------
template <int MODE, int TM, int TN, int OCC>
__global__ __launch_bounds__(256, OCC) void gemm_bt(
    const __hip_bfloat16* __restrict__ A, const __hip_bfloat16* __restrict__ Bt,
    int M, int N, int K, const float* __restrict__ bq,
    const float* __restrict__ bk, const float* __restrict__ bv,
    __hip_bfloat16* __restrict__ Qb, __hip_bfloat16* __restrict__ Kb,
    _Float16* __restrict__ Vt, float* __restrict__ outf) {
  constexpr int MI = TM / 32, NJ = TN / 32;  // acc tile dims per wave
  __shared__ __align__(16) char As[TM * 128];  // TM rows x 64 bf16
  __shared__ __align__(16) char Bs[TN * 128];
  const int tid = threadIdx.x;
  const int wave = tid >> 6, lane = tid & 63;
  const int quad = lane >> 4, l16 = lane & 15;
  const int bm = blockIdx.x * TM, bn = blockIdx.y * TN;
  const int wm = (wave >> 1) * (TM / 2), wn = (wave & 1) * (TN / 2);
  const int sw = l16 & 7;

  floatx4 acc[MI][NJ] = {};

  for (int k0 = 0; k0 < K; k0 += 64) {
#pragma unroll
    for (int i = 0; i < TM / 32; ++i) {
      const int p = tid + i * 256;
      const int r = p >> 3, cc = (p & 7) ^ (r & 7);
      async_copy16(A + (int64_t)(bm + r) * K + k0 + cc * 8, As + p * 16);
    }
#pragma unroll
    for (int i = 0; i < TN / 32; ++i) {
      const int p = tid + i * 256;
      const int r = p >> 3, cc = (p & 7) ^ (r & 7);
      async_copy16(Bt + (int64_t)(bn + r) * K + k0 + cc * 8, Bs + p * 16);
    }
    __syncthreads();
    bf16x8 af[MI][2], bfr[NJ][2];
#pragma unroll
    for (int i = 0; i < MI; ++i)
#pragma unroll
      for (int h = 0; h < 2; ++h)
        af[i][h] = *(const bf16x8*)(As + (wm + i * 16 + l16) * 128 +
                                    (((h * 4 + quad) ^ sw) << 4));
#pragma unroll
    for (int j = 0; j < NJ; ++j)
#pragma unroll
      for (int h = 0; h < 2; ++h)
        bfr[j][h] = *(const bf16x8*)(Bs + (wn + j * 16 + l16) * 128 +
                                     (((h * 4 + quad) ^ sw) << 4));
#pragma unroll
    for (int i = 0; i < MI; ++i)
#pragma unroll
      for (int j = 0; j < NJ; ++j)
#pragma unroll
        for (int h = 0; h < 2; ++h)
          acc[i][j] = mfma_16x16x32(af[i][h], bfr[j][h], acc[i][j]);
    __syncthreads();
  }

  if (MODE == 1) {
#pragma unroll
    for (int i = 0; i < MI; ++i)
#pragma unroll
      for (int j = 0; j < NJ; ++j) {
        const int n = bn + wn + j * 16 + l16;
#pragma unroll
        for (int r = 0; r < 4; ++r) {
          const int m = bm + wm + i * 16 + quad * 4 + r;
          outf[(int64_t)m * N + n] = acc[i][j][r];
        }
      }
  } else if (bn < 2048) {
    // ---- Q / K epilogue: bias (+QSCALE for Q), bf16 [B,H,S,64] ----
#pragma unroll
    for (int i = 0; i < MI; ++i)
#pragma unroll
      for (int j = 0; j < NJ; ++j) {
        const int n = bn + wn + j * 16 + l16;
        const int which = n >> 10, nn = n & 1023;
        const int h = nn >> 6, d = nn & 63;
        const float* bias = (which == 0) ? bq : bk;
#pragma unroll
        for (int r = 0; r < 4; ++r) {
          const int m = bm + wm + i * 16 + quad * 4 + r;
          const int b = m >> 11, s = m & 2047;
          float v = acc[i][j][r] + bias[nn];
          if (which == 0) v *= QSCALE;
          ((which == 0) ? Qb : Kb)[((int64_t)(b * 16 + h) * 2048 + s) * 64 + d] =
              __float2bfloat16(v);
        }
      }
  } else {
    // ---- V epilogue: LDS transpose -> Vt[B,H,64,S], coalesced rows ----
    char* scr = (wave & 1) ? Bs : As;  // >=8 KB per wave
    const int h = ((bn + wn) & 1023) >> 6;
    const int bb = (bm + wm) >> 11;
    const int sbase = (bm + wm) & 2047;
    _Float16* dstV = Vt + (int64_t)(bb * 16 + h) * 64 * 2048;
#pragma unroll
    for (int phase = 0; phase < 2; ++phase) {
      __syncthreads();
      if ((wave >> 1) == phase) {
#pragma unroll
        for (int i = 0; i < 4; ++i)
#pragma unroll
          for (int j = 0; j < 4; ++j) {
            const int d = j * 16 + l16;
#pragma unroll
            for (int r = 0; r < 4; ++r) {
              const int s = i * 16 + quad * 4 + r;
              *(_Float16*)(scr + VS(d, s)) =
                  (_Float16)(acc[i][j][r] + bv[((bn + wn) & 1023) + d]);
            }
          }
      }
      __syncthreads();
      if ((wave >> 1) == phase) {
#pragma unroll
        for (int it = 0; it < 8; ++it) {
          const int idx = lane + it * 64;  // [0,512)
          const int d = idx >> 3, sc = idx & 7;
          const half8 vv =
              *(const half8*)(scr + d * 128 + ((sc ^ (d & 7)) << 4));
          *(half8*)(dstV + (int64_t)d * 2048 + sbase + sc * 8) = vv;
        }
      }
    }
  }
}

// ---------------------------------------------------------------------------
// Flash attention v22 = v14 (paired q-chunks; session-best measured total
// 167.66 us, passed) + T5 s_setprio(1) around the MFMA clusters.
// Rationale: rounds 8-9's key-split rewrite NaN'd twice with no observable
// diagnostics -- parked. Re-anchor on the best-known-good structure. T5
// evidence: m191 attn +4-7% when co-resident blocks run at independent
// phases (v14: 2 independent blocks/CU, no inter-block sync); m190 shows
// no effect on lockstep GEMM, so the GEMMs stay untouched. setprio is a
// pure scheduler hint -- zero correctness risk.
// v14 recap: each block owns TWO q-chunks (cH=31-p, cL=p) and reuses every
// staged K/V tile + every LDS kfr/vfr fragment read for both chunks while
// kt<=cL. Tiles/bh: 528 -> 392. Grid 512 x 256 threads; bh%8 == bx%8 keeps
// each head's blocks on one XCD.
// ---------------------------------------------------------------------------
__global__ __launch_bounds__(256, 2) void attn_kernel(
    const __hip_bfloat16* __restrict__ Qb, const __hip_bfloat16* __restrict__ Kb,
    const _Float16* __restrict__ Vt, __hip_bfloat16* __restrict__ Ab) {
  // [0,16K): K bufs (2 x 8 KB bf16 64x64)  [16K,32K): V bufs (2 x 8 KB fp16)
  __shared__ __align__(16) char smem[32768];
  const int tid = threadIdx.x;
  const int wave = tid >> 6, lane = tid & 63;
  const int quad = lane >> 4, l16 = lane & 15;
  const int pr = (int)(blockIdx.x >> 5);  // pair index, heavy pairs first
  const int bh = blockIdx.x & 31;
  const int cH = 31 - pr, cL = pr;        // paired chunks (heavy, light)
  const int qH = cH * 64 + wave * 16;     // this wave's 16 rows of chunk H
  const int qL = cL * 64 + wave * 16;     // ... and of chunk L
  const int ktmax = cH;                   // uniform across waves

  const __hip_bfloat16* Qh = Qb + (int64_t)bh * 2048 * 64;
  const __hip_bfloat16* Kh = Kb + (int64_t)bh * 2048 * 64;
  const _Float16* Vh = Vt + (int64_t)bh * 64 * 2048;

  // Q B-fragments (16x16x32): Q[qrow=l16][d=h*32+quad*8+j]
  bf16x8 qfH[2], qfL[2];
#pragma unroll
  for (int h = 0; h < 2; ++h) {
    qfH[h] = *(const bf16x8*)&Qh[(int64_t)(qH + l16) * 64 + h * 32 + quad * 8];
    qfL[h] = *(const bf16x8*)&Qh[(int64_t)(qL + l16) * 64 + h * 32 + quad * 8];
  }

  floatx4 oH[4] = {}, oL[4] = {};  // O^T[dt][C: row=d(quad*4+r), col=qrow(l16)]
  float lsH = 0.f, lsL = 0.f;

  auto stage = [&](int buf, int k0s) {
#pragma unroll
    for (int i = 0; i < 2; ++i) {
      const int p = tid + i * 256;  // [0,512)
      const int r = p >> 3, cc = (p & 7) ^ (r & 7);
      async_copy16(Kh + (int64_t)(k0s + r) * 64 + cc * 8,
                   smem + buf * 8192 + p * 16);
      async_copy16(Vh + (int64_t)r * 2048 + k0s + cc * 8,
                   smem + 16384 + buf * 8192 + p * 16);
    }
  };

  stage(0, 0);
  for (int kt = 0; kt <= ktmax; ++kt) {
    const int k0 = kt * 64;
    const int cur = kt & 1;
    __syncthreads();  // buf[cur] DMA complete; prev tile's readers done
    if (kt < ktmax) stage(cur ^ 1, k0 + 64);

    const char* kb = smem + cur * 8192;
    const char* vb = smem + 16384 + cur * 8192;
    const int sw = l16 & 7;
    const bool doL = (kt <= cL);

    bf16x8 kfr[4][2];
#pragma unroll
    for (int kk = 0; kk < 4; ++kk)
#pragma unroll
      for (int h = 0; h < 2; ++h)
        kfr[kk][h] = *(const bf16x8*)(kb + (kk * 16 + l16) * 128 +
                                      (((h * 4 + quad) ^ sw) << 4));

    // S^T = K Q^T : C holds S^T[key=quad*4+r][qrow=l16]
    floatx4 stH[4], stL[4];
    __builtin_amdgcn_s_setprio(1);
#pragma unroll
    for (int kk = 0; kk < 4; ++kk) {
      floatx4 z = {};
      z = mfma_16x16x32(kfr[kk][0], qfH[0], z);
      stH[kk] = mfma_16x16x32(kfr[kk][1], qfH[1], z);
    }
    if (doL) {
#pragma unroll
      for (int kk = 0; kk < 4; ++kk) {
        floatx4 z = {};
        z = mfma_16x16x32(kfr[kk][0], qfL[0], z);
        stL[kk] = mfma_16x16x32(kfr[kk][1], qfL[1], z);
      }
    }
    __builtin_amdgcn_s_setprio(0);

    half4 vfr[4][4];
#pragma unroll
    for (int dt = 0; dt < 4; ++dt)
#pragma unroll
      for (int kk = 0; kk < 4; ++kk)
        vfr[dt][kk] = *(const half4*)(vb + (dt * 16 + l16) * 128 +
                                      (((kk * 2 + (quad >> 1)) ^ sw) << 4) +
                                      (quad & 1) * 8);

    // ---- H chunk: P = exp2(S), mask on diagonal tile, PV ----
    {
      const bool masked = (kt == cH);
      half4 pf[4];
#pragma unroll
      for (int kk = 0; kk < 4; ++kk) {
#pragma unroll
        for (int r = 0; r < 4; ++r) {
          const int key = k0 + kk * 16 + quad * 4 + r;
          float p = __builtin_amdgcn_exp2f(stH[kk][r]);
          if (masked && key > qH + l16) p = 0.f;
          lsH += p;
          pf[kk][r] = (_Float16)p;
        }
      }
      __builtin_amdgcn_s_setprio(1);
#pragma unroll
      for (int dt = 0; dt < 4; ++dt)
#pragma unroll
        for (int kk = 0; kk < 4; ++kk)
          oH[dt] = mfma_16x16x16_f16(vfr[dt][kk], pf[kk], oH[dt]);
      __builtin_amdgcn_s_setprio(0);
    }
    // ---- L chunk: same tile, reused kfr/vfr; active while kt<=cL ----
    if (doL) {
      const bool masked = (kt == cL);
      half4 pf[4];
#pragma unroll
      for (int kk = 0; kk < 4; ++kk) {
#pragma unroll
        for (int r = 0; r < 4; ++r) {
          const int key = k0 + kk * 16 + quad * 4 + r;
          float p = __builtin_amdgcn_exp2f(stL[kk][r]);
          if (masked && key > qL + l16) p = 0.f;
          lsL += p;
          pf[kk][r] = (_Float16)p;
        }
      }
      __builtin_amdgcn_s_setprio(1);
#pragma unroll
      for (int dt = 0; dt < 4; ++dt)
#pragma unroll
        for (int kk = 0; kk < 4; ++kk)
          oL[dt] = mfma_16x16x16_f16(vfr[dt][kk], pf[kk], oL[dt]);
      __builtin_amdgcn_s_setprio(0);
    }
  }

  // ---- finalize: l is split across the 4 quads per qrow; reduce ----
  lsH += __shfl_xor(lsH, 16, 64);
  lsH += __shfl_xor(lsH, 32, 64);
  lsL += __shfl_xor(lsL, 16, 64);
  lsL += __shfl_xor(lsL, 32, 64);
  const float invH = 1.0f / lsH;
  const float invL = 1.0f / lsL;

  // store bf16 [B,S,H*64]: row = q+l16, cols h*64 + dt*16 + quad*4 + r
  const int b = bh >> 4, h = bh & 15;
#pragma unroll
  for (int dt = 0; dt < 4; ++dt) {
    u16x4 packH, packL;
#pragma unroll
    for (int r = 0; r < 4; ++r) {
      packH[r] = __builtin_bit_cast(unsigned short,
                                    __float2bfloat16(oH[dt][r] * invH));
      packL[r] = __builtin_bit_cast(unsigned short,
                                    __float2bfloat16(oL[dt][r] * invL));
    }
    *(u16x4*)&Ab[(int64_t)(b * 2048 + qH + l16) * 1024 + h * 64 + dt * 16 +
                 quad * 4] = packH;
    *(u16x4*)&Ab[(int64_t)(b * 2048 + qL + l16) * 1024 + h * 64 + dt * 16 +
                 quad * 4] = packL;
  }
}

// ---------------------------------------------------------------------------
// Workspace layout (bytes), needs 40 MB:
//   [0,  8M): xb  (x as bf16, 4096x1024)  -- reused as Ab (attn out) later
//   [8, 14M): Wt  (Wq|Wk|Wv transposed bf16, 3072x1024)
//   [14,16M): Wot (Wo transposed bf16, 1024x1024)
//   [16,24M): Qb  [B,H,S,64] bf16 (pre-scaled by QSCALE)
//   [24,32M): Kb  [B,H,S,64] bf16
//   [32,40M): Vt  [B,H,64,S] fp16 (written directly by gemm_bt<0> epilogue)
// ---------------------------------------------------------------------------
extern "C" void kernel_launch(void* const* d_in, const int* in_sizes, int n_in,
                              void* d_out, int out_size, void* d_ws,
                              size_t ws_size, hipStream_t stream) {
  const float* x = (const float*)d_in[0];
  const float* Wq = (const float*)d_in[1];
  const float* bq = (const float*)d_in[2];
  const float* Wk = (const float*)d_in[3];
  const float* bk = (const float*)d_in[4];
  const float* Wv = (const float*)d_in[5];
  const float* bv = (const float*)d_in[6];
  const float* Wo = (const float*)d_in[7];
  float* out = (float*)d_out;

  char* ws = (char*)d_ws;
  __hip_bfloat16* xb = (__hip_bfloat16*)(ws);
  __hip_bfloat16* Wt = (__hip_bfloat16*)(ws + (8ll << 20));
  __hip_bfloat16* Wot = (__hip_bfloat16*)(ws + (14ll << 20));
  __hip_bfloat16* Qb = (__hip_bfloat16*)(ws + (16ll << 20));
  __hip_bfloat16* Kb = (__hip_bfloat16*)(ws + (24ll << 20));
  _Float16* Vt = (_Float16*)(ws + (32ll << 20));
  __hip_bfloat16* Ab = xb;  // x dead after QKV GEMM

  prep<<<dim3(32, 32, 5), dim3(32, 8), 0, stream>>>(x, Wq, Wk, Wv, Wo, xb, Wt,
                                                    Wot);
  gemm_bt<0, 128, 128, 3><<<dim3(32, 24), 256, 0, stream>>>(
      xb, Wt, 4096, 3072, 1024, bq, bk, bv, Qb, Kb, Vt, nullptr);
  attn_kernel<<<dim3(512), 256, 0, stream>>>(Qb, Kb, Vt, Ab);
  gemm_bt<1, 128, 64, 2><<<dim3(32, 16), 256, 0, stream>>>(
      Ab, Wot, 4096, 1024, 1024, nullptr, nullptr, nullptr, nullptr, nullptr,
      nullptr, out);
}